// Round 2
// baseline (254.758 us; speedup 1.0000x reference)
//
#include <hip/hip_runtime.h>
#include <hip/hip_bf16.h>
#include <hip/hip_fp16.h>

typedef unsigned int u32;
typedef unsigned short u16;
typedef __attribute__((ext_vector_type(8))) short short8;
typedef __attribute__((ext_vector_type(4))) float f32x4;

#define B_DIM 256
#define L_DIM 512
#define A_DIM 2048
#define W_DIM 64

__device__ __forceinline__ u32 fenc(float f){ u32 u=__float_as_uint(f); return (u>>31)? ~u : (u|0x80000000u); }
__device__ __forceinline__ float fdec(u32 k){ return (k>>31)? __uint_as_float(k&0x7FFFFFFFu) : __uint_as_float(~k); }
__device__ __forceinline__ u16 f2bf(float f){
  u32 u=__float_as_uint(f);
  u32 r=(u + 0x7FFFu + ((u>>16)&1u))>>16;
  return (u16)r;
}
__device__ __forceinline__ float bf2f(u16 b){ return __uint_as_float((u32)b << 16); }
__device__ __forceinline__ u16 f2h(float f){ _Float16 h = (_Float16)f; return __builtin_bit_cast(u16, h); }
__device__ __forceinline__ float h2f(u16 b){ _Float16 h = __builtin_bit_cast(_Float16, b); return (float)h; }

// f32 -> bf16 convert, n % 4 == 0
__global__ __launch_bounds__(256) void cvt_kernel(const float* __restrict__ src, u16* __restrict__ dst, int n){
  int stride = gridDim.x*blockDim.x*4;
  for (int i = (blockIdx.x*blockDim.x + threadIdx.x)*4; i < n; i += stride){
    float4 v = *(const float4*)(src + i);
    ushort4 o;
    o.x = f2bf(v.x); o.y = f2bf(v.y); o.z = f2bf(v.z); o.w = f2bf(v.w);
    *(ushort4*)(dst + i) = o;
  }
}

__device__ __forceinline__ void cvt_seg(const float* __restrict__ src, u16* __restrict__ dst, int n, int tid, int stride){
  for (int i = tid*4; i < n; i += stride){
    float4 v = *(const float4*)(src + i);
    ushort4 o;
    o.x = f2bf(v.x); o.y = f2bf(v.y); o.z = f2bf(v.z); o.w = f2bf(v.w);
    *(ushort4*)(dst + i) = o;
  }
}

// 5 small conversions in one launch
__global__ __launch_bounds__(256) void cvt5_kernel(
    const float* s0, u16* d0, int n0,
    const float* s1, u16* d1, int n1,
    const float* s2, u16* d2, int n2,
    const float* s3, u16* d3, int n3,
    const float* s4, u16* d4, int n4){
  int tid = blockIdx.x*blockDim.x + threadIdx.x;
  int stride = gridDim.x*blockDim.x*4;
  cvt_seg(s0,d0,n0,tid,stride);
  cvt_seg(s1,d1,n1,tid,stride);
  cvt_seg(s2,d2,n2,tid,stride);
  cvt_seg(s3,d3,n3,tid,stride);
  cvt_seg(s4,d4,n4,tid,stride);
}

// Fused K+V GEMM: A [M][512] bf16 shared; K->f16 (+per-w max), V->bf16.
// LDS swizzle (rule #21): linear LDS dest (global_load_lds), pre-swizzled
// global source chunk, matching XOR on the fragment read.
__global__ __launch_bounds__(256) void gemm_kv(
    const u16* __restrict__ Ab, const u16* __restrict__ Bk, const u16* __restrict__ Bv,
    u16* __restrict__ Kh, u16* __restrict__ Vb, u32* __restrict__ menc)
{
  __shared__ u16 As[128*32];
  __shared__ u16 Ks[128*32];
  __shared__ u16 Vs[128*32];
  __shared__ float wred[4];

  const int t = threadIdx.x;
  const int lane = t & 63;
  const int wave = t >> 6;
  const int wm = wave >> 1, wn = wave & 1;
  const int m0 = blockIdx.y * 128;
  const int n0 = blockIdx.x * 128;
  const int N = A_DIM, Kd = L_DIM;

  f32x4 ak[4][4], av[4][4];
  #pragma unroll
  for (int i=0;i<4;++i)
    #pragma unroll
    for (int j=0;j<4;++j){ ak[i][j] = (f32x4)0.f; av[i][j] = (f32x4)0.f; }

  const int row_in = t >> 2;                        // 0..63
  const int cg = (((t&3) ^ ((t>>3)&3)))*8;          // swizzled source chunk (shorts)
  const int wbase = (t & 192) * 8;                  // wave-uniform LDS short offset

  for (int kt = 0; kt < (L_DIM>>5); ++kt){
    const int k0 = kt << 5;
    #pragma unroll
    for (int i = 0; i < 2; ++i){
      const u16* ga = Ab + (size_t)(m0 + i*64 + row_in)*Kd + k0 + cg;
      const u16* gk = Bk + (size_t)(n0 + i*64 + row_in)*Kd + k0 + cg;
      const u16* gv = Bv + (size_t)(n0 + i*64 + row_in)*Kd + k0 + cg;
      __builtin_amdgcn_global_load_lds((const __attribute__((address_space(1))) u32*)ga,
          (__attribute__((address_space(3))) u32*)(As + i*2048 + wbase), 16, 0, 0);
      __builtin_amdgcn_global_load_lds((const __attribute__((address_space(1))) u32*)gk,
          (__attribute__((address_space(3))) u32*)(Ks + i*2048 + wbase), 16, 0, 0);
      __builtin_amdgcn_global_load_lds((const __attribute__((address_space(1))) u32*)gv,
          (__attribute__((address_space(3))) u32*)(Vs + i*2048 + wbase), 16, 0, 0);
    }
    __syncthreads();
    short8 af[4], bk4[4], bv4[4];
    const int fr = lane & 15;
    const int k = lane >> 4;
    #pragma unroll
    for (int i=0;i<4;++i){
      const int rowA = wm*64 + i*16 + fr;
      const int rowB = wn*64 + i*16 + fr;
      const int ca = (k ^ ((rowA>>1)&3))*8;
      const int cb = (k ^ ((rowB>>1)&3))*8;
      af[i]  = *(const short8*)(As + rowA*32 + ca);
      bk4[i] = *(const short8*)(Ks + rowB*32 + cb);
      bv4[i] = *(const short8*)(Vs + rowB*32 + cb);
    }
    #pragma unroll
    for (int i=0;i<4;++i)
      #pragma unroll
      for (int j=0;j<4;++j){
        ak[i][j] = __builtin_amdgcn_mfma_f32_16x16x32_bf16(af[i], bk4[j], ak[i][j], 0, 0, 0);
        av[i][j] = __builtin_amdgcn_mfma_f32_16x16x32_bf16(af[i], bv4[j], av[i][j], 0, 0, 0);
      }
    __syncthreads();
  }

  float vmax = -3.4e38f;
  #pragma unroll
  for (int i=0;i<4;++i){
    const int grow_base = m0 + wm*64 + i*16 + ((lane>>4)<<2);
    #pragma unroll
    for (int j=0;j<4;++j){
      const int gcol = n0 + wn*64 + j*16 + (lane & 15);
      #pragma unroll
      for (int r=0;r<4;++r){
        const size_t idx = (size_t)(grow_base + r)*N + gcol;
        float kv = ak[i][j][r];
        Kh[idx] = f2h(kv);
        vmax = fmaxf(vmax, kv);
        Vb[idx] = f2bf(av[i][j][r]);
      }
    }
  }
  #pragma unroll
  for (int off=32; off; off>>=1) vmax = fmaxf(vmax, __shfl_xor(vmax, off));
  if (lane == 0) wred[wave] = vmax;
  __syncthreads();
  if (t == 0){
    float m = fmaxf(fmaxf(wred[0], wred[1]), fmaxf(wred[2], wred[3]));
    atomicMax(menc + (m0 >> 8), fenc(m));
  }
}

// NT GEMM for the small projections: C[m,n] = sum_k A[m,k]*B[n,k].
// MODE 2: store f32, MODE 3: store f32 (final output)
template<int MODE>
__global__ __launch_bounds__(256) void gemm_nt(
    const u16* __restrict__ Ab, const u16* __restrict__ Bb,
    float* __restrict__ Cf, int M, int N, int Kd)
{
  __shared__ u16 As[128*32];
  __shared__ u16 Bs[128*32];

  const int t = threadIdx.x;
  const int lane = t & 63;
  const int wave = t >> 6;
  const int wm = wave >> 1, wn = wave & 1;
  const int m0 = blockIdx.y * 128;
  const int n0 = blockIdx.x * 128;

  f32x4 acc[4][4];
  #pragma unroll
  for (int i=0;i<4;++i)
    #pragma unroll
    for (int j=0;j<4;++j) acc[i][j] = (f32x4)0.f;

  const int row_in = t >> 2;
  const int koff8 = (t & 3) * 8;
  const int wbase = (t & 192) * 8;

  const int nK = Kd >> 5;
  for (int kt = 0; kt < nK; ++kt){
    const int k0 = kt << 5;
    #pragma unroll
    for (int i = 0; i < 2; ++i){
      const u16* ga = Ab + (size_t)(m0 + i*64 + row_in)*Kd + k0 + koff8;
      const u16* gb = Bb + (size_t)(n0 + i*64 + row_in)*Kd + k0 + koff8;
      __builtin_amdgcn_global_load_lds((const __attribute__((address_space(1))) u32*)ga,
          (__attribute__((address_space(3))) u32*)(As + i*2048 + wbase), 16, 0, 0);
      __builtin_amdgcn_global_load_lds((const __attribute__((address_space(1))) u32*)gb,
          (__attribute__((address_space(3))) u32*)(Bs + i*2048 + wbase), 16, 0, 0);
    }
    __syncthreads();
    short8 af[4], bf[4];
    const int fr = lane & 15;
    const int fk = (lane >> 4) * 8;
    #pragma unroll
    for (int i=0;i<4;++i){
      af[i] = *(const short8*)(As + (wm*64 + i*16 + fr)*32 + fk);
      bf[i] = *(const short8*)(Bs + (wn*64 + i*16 + fr)*32 + fk);
    }
    #pragma unroll
    for (int i=0;i<4;++i)
      #pragma unroll
      for (int j=0;j<4;++j)
        acc[i][j] = __builtin_amdgcn_mfma_f32_16x16x32_bf16(af[i], bf[j], acc[i][j], 0, 0, 0);
    __syncthreads();
  }

  #pragma unroll
  for (int i=0;i<4;++i){
    const int grow_base = m0 + wm*64 + i*16 + ((lane>>4)<<2);
    #pragma unroll
    for (int j=0;j<4;++j){
      const int gcol = n0 + wn*64 + j*16 + (lane & 15);
      #pragma unroll
      for (int r=0;r<4;++r)
        Cf[(size_t)(grow_base + r)*N + gcol] = acc[i][j][r];
    }
  }
}

// context + gating, 4 elems/thread: g[b,a] = sigmoid(Q) * (sum_w e*V) / (1e-8 + sum_w e)
__global__ __launch_bounds__(256) void reduce_kernel(
    const u16* __restrict__ Kh, const u16* __restrict__ Vb,
    const float* __restrict__ Qf, const u32* __restrict__ menc,
    u16* __restrict__ g)
{
  __shared__ float ms[W_DIM];
  if (threadIdx.x < W_DIM) ms[threadIdx.x] = fdec(menc[threadIdx.x]);
  __syncthreads();
  const int total = B_DIM * A_DIM;
  const int idx = (blockIdx.x*blockDim.x + threadIdx.x) * 4;  // grid covers exactly

  float num0=0.f, num1=0.f, num2=0.f, num3=0.f;
  float den0=1e-8f, den1=1e-8f, den2=1e-8f, den3=1e-8f;
  #pragma unroll 2
  for (int w = 0; w < W_DIM; ++w){
    const size_t off = (size_t)w*total + idx;
    ushort4 kh = *(const ushort4*)(Kh + off);
    ushort4 vb = *(const ushort4*)(Vb + off);
    const float mw = ms[w];
    float e0 = __expf(h2f(kh.x) - mw); num0 += e0*bf2f(vb.x); den0 += e0;
    float e1 = __expf(h2f(kh.y) - mw); num1 += e1*bf2f(vb.y); den1 += e1;
    float e2 = __expf(h2f(kh.z) - mw); num2 += e2*bf2f(vb.z); den2 += e2;
    float e3 = __expf(h2f(kh.w) - mw); num3 += e3*bf2f(vb.w); den3 += e3;
  }
  float4 q = *(const float4*)(Qf + idx);
  ushort4 o;
  o.x = f2bf(num0/den0/(1.f + __expf(-q.x)));
  o.y = f2bf(num1/den1/(1.f + __expf(-q.y)));
  o.z = f2bf(num2/den2/(1.f + __expf(-q.z)));
  o.w = f2bf(num3/den3/(1.f + __expf(-q.w)));
  *(ushort4*)(g + idx) = o;
}

extern "C" void kernel_launch(void* const* d_in, const int* in_sizes, int n_in,
                              void* d_out, int out_size, void* d_ws, size_t ws_size,
                              hipStream_t stream){
  const float* zc = (const float*)d_in[0];
  const float* zw = (const float*)d_in[1];
  const float* Wq = (const float*)d_in[2];
  const float* Wk = (const float*)d_in[3];
  const float* Wv = (const float*)d_in[4];
  const float* Wo = (const float*)d_in[5];
  float* out = (float*)d_out;

  char* ws = (char*)d_ws;
  size_t off = 0;
  auto alloc = [&](size_t bytes)->void*{ void* p = ws + off; off += (bytes + 255) & ~(size_t)255; return p; };
  u16*  Zb   = (u16*) alloc((size_t)W_DIM*B_DIM*L_DIM*2);   // 16.8 MB
  u16*  zcb  = (u16*) alloc((size_t)B_DIM*L_DIM*2);
  u16*  Wqb  = (u16*) alloc((size_t)A_DIM*L_DIM*2);
  u16*  Wkb  = (u16*) alloc((size_t)A_DIM*L_DIM*2);
  u16*  Wvb  = (u16*) alloc((size_t)A_DIM*L_DIM*2);
  u16*  Wob  = (u16*) alloc((size_t)L_DIM*A_DIM*2);
  u16*  Kh   = (u16*) alloc((size_t)W_DIM*B_DIM*A_DIM*2);   // 67 MB (f16)
  u16*  Vb   = (u16*) alloc((size_t)W_DIM*B_DIM*A_DIM*2);   // 67 MB (bf16)
  float* Qf  = (float*)alloc((size_t)B_DIM*A_DIM*4);
  u16*  g    = (u16*) alloc((size_t)B_DIM*A_DIM*2);
  u32*  menc = (u32*) alloc(W_DIM*4);

  cvt_kernel<<<512, 256, 0, stream>>>(zw, Zb, W_DIM*B_DIM*L_DIM);
  cvt5_kernel<<<256, 256, 0, stream>>>(zc, zcb, B_DIM*L_DIM,
                                       Wq, Wqb, A_DIM*L_DIM,
                                       Wk, Wkb, A_DIM*L_DIM,
                                       Wv, Wvb, A_DIM*L_DIM,
                                       Wo, Wob, L_DIM*A_DIM);
  hipMemsetAsync(menc, 0, W_DIM*4, stream);

  dim3 blk(256);
  // K (f16) + V (bf16) fused, per-w max: M=W*B=16384, N=A, K=L
  gemm_kv<<<dim3(A_DIM/128, (W_DIM*B_DIM)/128), blk, 0, stream>>>(Zb, Wkb, Wvb, Kh, Vb, menc);
  // Q = zc @ Wq^T -> f32
  gemm_nt<2><<<dim3(A_DIM/128, B_DIM/128), blk, 0, stream>>>(zcb, Wqb, Qf, B_DIM, A_DIM, L_DIM);
  // g = sigmoid(Q) * context
  reduce_kernel<<<(B_DIM*A_DIM)/(256*4), blk, 0, stream>>>(Kh, Vb, Qf, menc, g);
  // out = g @ Wo^T: M=B, N=L, K=A
  gemm_nt<3><<<dim3(L_DIM/128, B_DIM/128), blk, 0, stream>>>(g, Wob, out, B_DIM, L_DIM, A_DIM);
}

// Round 3
// 198.613 us; speedup vs baseline: 1.2827x; 1.2827x over previous
//
#include <hip/hip_runtime.h>
#include <hip/hip_bf16.h>
#include <hip/hip_fp16.h>

typedef unsigned int u32;
typedef unsigned short u16;
typedef __attribute__((ext_vector_type(8))) short short8;
typedef __attribute__((ext_vector_type(4))) float f32x4;

#define B_DIM 256
#define L_DIM 512
#define A_DIM 2048
#define W_DIM 64

__device__ __forceinline__ u32 fenc(float f){ u32 u=__float_as_uint(f); return (u>>31)? ~u : (u|0x80000000u); }
__device__ __forceinline__ float fdec(u32 k){ return (k>>31)? __uint_as_float(k&0x7FFFFFFFu) : __uint_as_float(~k); }
__device__ __forceinline__ u16 f2bf(float f){
  u32 u=__float_as_uint(f);
  u32 r=(u + 0x7FFFu + ((u>>16)&1u))>>16;
  return (u16)r;
}
__device__ __forceinline__ float bf2f(u16 b){ return __uint_as_float((u32)b << 16); }
__device__ __forceinline__ u16 f2h(float f){ _Float16 h = (_Float16)f; return __builtin_bit_cast(u16, h); }
__device__ __forceinline__ float h2f(u16 b){ _Float16 h = __builtin_bit_cast(_Float16, b); return (float)h; }

// f32 -> bf16 convert, n % 4 == 0
__global__ __launch_bounds__(256) void cvt_kernel(const float* __restrict__ src, u16* __restrict__ dst, int n){
  int stride = gridDim.x*blockDim.x*4;
  for (int i = (blockIdx.x*blockDim.x + threadIdx.x)*4; i < n; i += stride){
    float4 v = *(const float4*)(src + i);
    ushort4 o;
    o.x = f2bf(v.x); o.y = f2bf(v.y); o.z = f2bf(v.z); o.w = f2bf(v.w);
    *(ushort4*)(dst + i) = o;
  }
}

__device__ __forceinline__ void cvt_seg(const float* __restrict__ src, u16* __restrict__ dst, int n, int tid, int stride){
  for (int i = tid*4; i < n; i += stride){
    float4 v = *(const float4*)(src + i);
    ushort4 o;
    o.x = f2bf(v.x); o.y = f2bf(v.y); o.z = f2bf(v.z); o.w = f2bf(v.w);
    *(ushort4*)(dst + i) = o;
  }
}

__global__ __launch_bounds__(256) void cvt5_kernel(
    const float* s0, u16* d0, int n0,
    const float* s1, u16* d1, int n1,
    const float* s2, u16* d2, int n2,
    const float* s3, u16* d3, int n3,
    const float* s4, u16* d4, int n4){
  int tid = blockIdx.x*blockDim.x + threadIdx.x;
  int stride = gridDim.x*blockDim.x*4;
  cvt_seg(s0,d0,n0,tid,stride);
  cvt_seg(s1,d1,n1,tid,stride);
  cvt_seg(s2,d2,n2,tid,stride);
  cvt_seg(s3,d3,n3,tid,stride);
  cvt_seg(s4,d4,n4,tid,stride);
}

// NT GEMM: C[m,n] = sum_k A[m,k]*B[n,k], A:[M][Kd] bf16, B:[N][Kd] bf16.
// 128x128 tile, 4 waves, BK=32, global_load_lds + both-sides LDS swizzle
// (linear LDS dest, pre-swizzled global source chunk, matching XOR on read)
// + bijective XCD-aware block swizzle (requires nwg % 8 == 0).
// MODE 0: store f16 + per-w (row/256) max via encoded atomicMax (K)
// MODE 1: store bf16 (V)
// MODE 2: store f32 (Q)
// MODE 3: store f32 (final output)
template<int MODE>
__global__ __launch_bounds__(256) void gemm_nt(
    const u16* __restrict__ Ab, const u16* __restrict__ Bb,
    float* __restrict__ Cf, u16* __restrict__ Cu, u32* __restrict__ menc,
    int N, int Kd)
{
  __shared__ u16 As[128*32];
  __shared__ u16 Bs[128*32];
  __shared__ float wred[4];

  const int t = threadIdx.x;
  const int lane = t & 63;
  const int wave = t >> 6;
  const int wm = wave >> 1, wn = wave & 1;

  // XCD-aware bijective swizzle: XCD k gets a contiguous chunk of tiles
  const int nwg = gridDim.x * gridDim.y;
  const int id = blockIdx.x + gridDim.x * blockIdx.y;
  const int chunk = nwg >> 3;
  const int swz = (id & 7) * chunk + (id >> 3);
  const int bx = swz % gridDim.x;
  const int by = swz / gridDim.x;
  const int m0 = by * 128;
  const int n0 = bx * 128;

  f32x4 acc[4][4];
  #pragma unroll
  for (int i=0;i<4;++i)
    #pragma unroll
    for (int j=0;j<4;++j) acc[i][j] = (f32x4)0.f;

  const int row_in = t >> 2;                 // 0..63
  const int cg = ((t&3) ^ ((t>>3)&3)) * 8;   // swizzled source chunk (shorts)
  const int wbase = (t & 192) * 8;           // wave-uniform LDS short offset

  const int nK = Kd >> 5;
  for (int kt = 0; kt < nK; ++kt){
    const int k0 = kt << 5;
    #pragma unroll
    for (int i = 0; i < 2; ++i){
      const u16* ga = Ab + (size_t)(m0 + i*64 + row_in)*Kd + k0 + cg;
      const u16* gb = Bb + (size_t)(n0 + i*64 + row_in)*Kd + k0 + cg;
      __builtin_amdgcn_global_load_lds((const __attribute__((address_space(1))) u32*)ga,
          (__attribute__((address_space(3))) u32*)(As + i*2048 + wbase), 16, 0, 0);
      __builtin_amdgcn_global_load_lds((const __attribute__((address_space(1))) u32*)gb,
          (__attribute__((address_space(3))) u32*)(Bs + i*2048 + wbase), 16, 0, 0);
    }
    __syncthreads();
    short8 af[4], bf[4];
    const int fr = lane & 15;
    const int k = lane >> 4;
    #pragma unroll
    for (int i=0;i<4;++i){
      const int rowA = wm*64 + i*16 + fr;
      const int rowB = wn*64 + i*16 + fr;
      af[i] = *(const short8*)(As + rowA*32 + (k ^ ((rowA>>1)&3))*8);
      bf[i] = *(const short8*)(Bs + rowB*32 + (k ^ ((rowB>>1)&3))*8);
    }
    #pragma unroll
    for (int i=0;i<4;++i)
      #pragma unroll
      for (int j=0;j<4;++j)
        acc[i][j] = __builtin_amdgcn_mfma_f32_16x16x32_bf16(af[i], bf[j], acc[i][j], 0, 0, 0);
    __syncthreads();
  }

  float vmax = -3.4e38f;
  #pragma unroll
  for (int i=0;i<4;++i){
    const int grow_base = m0 + wm*64 + i*16 + ((lane>>4)<<2);
    #pragma unroll
    for (int j=0;j<4;++j){
      const int gcol = n0 + wn*64 + j*16 + (lane & 15);
      #pragma unroll
      for (int r=0;r<4;++r){
        float v = acc[i][j][r];
        const size_t idx = (size_t)(grow_base + r)*N + gcol;
        if constexpr (MODE == 0){ Cu[idx] = f2h(v); vmax = fmaxf(vmax, v); }
        else if constexpr (MODE == 1) Cu[idx] = f2bf(v);
        else Cf[idx] = v;
      }
    }
  }
  if constexpr (MODE == 0){
    #pragma unroll
    for (int off=32; off; off>>=1) vmax = fmaxf(vmax, __shfl_xor(vmax, off));
    if (lane == 0) wred[wave] = vmax;
    __syncthreads();
    if (t == 0){
      float m = fmaxf(fmaxf(wred[0], wred[1]), fmaxf(wred[2], wred[3]));
      atomicMax(menc + (m0 >> 8), fenc(m));
    }
  }
}

// context + gating, 4 elems/thread: g[b,a] = sigmoid(Q) * (sum_w e*V) / (1e-8 + sum_w e)
__global__ __launch_bounds__(256) void reduce_kernel(
    const u16* __restrict__ Kh, const u16* __restrict__ Vb,
    const float* __restrict__ Qf, const u32* __restrict__ menc,
    u16* __restrict__ g)
{
  __shared__ float ms[W_DIM];
  if (threadIdx.x < W_DIM) ms[threadIdx.x] = fdec(menc[threadIdx.x]);
  __syncthreads();
  const int total = B_DIM * A_DIM;
  const int idx = (blockIdx.x*blockDim.x + threadIdx.x) * 4;

  float num0=0.f, num1=0.f, num2=0.f, num3=0.f;
  float den0=1e-8f, den1=1e-8f, den2=1e-8f, den3=1e-8f;
  #pragma unroll 2
  for (int w = 0; w < W_DIM; ++w){
    const size_t off = (size_t)w*total + idx;
    ushort4 kh = *(const ushort4*)(Kh + off);
    ushort4 vb = *(const ushort4*)(Vb + off);
    const float mw = ms[w];
    float e0 = __expf(h2f(kh.x) - mw); num0 += e0*bf2f(vb.x); den0 += e0;
    float e1 = __expf(h2f(kh.y) - mw); num1 += e1*bf2f(vb.y); den1 += e1;
    float e2 = __expf(h2f(kh.z) - mw); num2 += e2*bf2f(vb.z); den2 += e2;
    float e3 = __expf(h2f(kh.w) - mw); num3 += e3*bf2f(vb.w); den3 += e3;
  }
  float4 q = *(const float4*)(Qf + idx);
  ushort4 o;
  o.x = f2bf(num0/den0/(1.f + __expf(-q.x)));
  o.y = f2bf(num1/den1/(1.f + __expf(-q.y)));
  o.z = f2bf(num2/den2/(1.f + __expf(-q.z)));
  o.w = f2bf(num3/den3/(1.f + __expf(-q.w)));
  *(ushort4*)(g + idx) = o;
}

extern "C" void kernel_launch(void* const* d_in, const int* in_sizes, int n_in,
                              void* d_out, int out_size, void* d_ws, size_t ws_size,
                              hipStream_t stream){
  const float* zc = (const float*)d_in[0];
  const float* zw = (const float*)d_in[1];
  const float* Wq = (const float*)d_in[2];
  const float* Wk = (const float*)d_in[3];
  const float* Wv = (const float*)d_in[4];
  const float* Wo = (const float*)d_in[5];
  float* out = (float*)d_out;

  char* ws = (char*)d_ws;
  size_t off = 0;
  auto alloc = [&](size_t bytes)->void*{ void* p = ws + off; off += (bytes + 255) & ~(size_t)255; return p; };
  u16*  Zb   = (u16*) alloc((size_t)W_DIM*B_DIM*L_DIM*2);   // 16.8 MB
  u16*  zcb  = (u16*) alloc((size_t)B_DIM*L_DIM*2);
  u16*  Wqb  = (u16*) alloc((size_t)A_DIM*L_DIM*2);
  u16*  Wkb  = (u16*) alloc((size_t)A_DIM*L_DIM*2);
  u16*  Wvb  = (u16*) alloc((size_t)A_DIM*L_DIM*2);
  u16*  Wob  = (u16*) alloc((size_t)L_DIM*A_DIM*2);
  u16*  Kh   = (u16*) alloc((size_t)W_DIM*B_DIM*A_DIM*2);   // 67 MB (f16)
  u16*  Vb   = (u16*) alloc((size_t)W_DIM*B_DIM*A_DIM*2);   // 67 MB (bf16)
  float* Qf  = (float*)alloc((size_t)B_DIM*A_DIM*4);
  u16*  g    = (u16*) alloc((size_t)B_DIM*A_DIM*2);
  u32*  menc = (u32*) alloc(W_DIM*4);

  cvt_kernel<<<512, 256, 0, stream>>>(zw, Zb, W_DIM*B_DIM*L_DIM);
  cvt5_kernel<<<256, 256, 0, stream>>>(zc, zcb, B_DIM*L_DIM,
                                       Wq, Wqb, A_DIM*L_DIM,
                                       Wk, Wkb, A_DIM*L_DIM,
                                       Wv, Wvb, A_DIM*L_DIM,
                                       Wo, Wob, L_DIM*A_DIM);
  hipMemsetAsync(menc, 0, W_DIM*4, stream);

  dim3 blk(256);
  // K (f16 + per-w max): M=W*B=16384, N=A=2048, K=L=512 -> grid 16x128 (nwg%8==0)
  gemm_nt<0><<<dim3(A_DIM/128, (W_DIM*B_DIM)/128), blk, 0, stream>>>(Zb, Wkb, nullptr, Kh, menc, A_DIM, L_DIM);
  // V (bf16)
  gemm_nt<1><<<dim3(A_DIM/128, (W_DIM*B_DIM)/128), blk, 0, stream>>>(Zb, Wvb, nullptr, Vb, nullptr, A_DIM, L_DIM);
  // Q = zc @ Wq^T -> f32, grid 16x2 (nwg=32, %8==0)
  gemm_nt<2><<<dim3(A_DIM/128, B_DIM/128), blk, 0, stream>>>(zcb, Wqb, Qf, nullptr, nullptr, A_DIM, L_DIM);
  // g = sigmoid(Q) * context
  reduce_kernel<<<(B_DIM*A_DIM)/(256*4), blk, 0, stream>>>(Kh, Vb, Qf, menc, g);
  // out = g @ Wo^T: M=B=256, N=L=512, K=A=2048, grid 4x2 (nwg=8)
  gemm_nt<3><<<dim3(L_DIM/128, B_DIM/128), blk, 0, stream>>>(g, Wob, out, nullptr, nullptr, L_DIM, A_DIM);
}

// Round 4
// 178.385 us; speedup vs baseline: 1.4281x; 1.1134x over previous
//
#include <hip/hip_runtime.h>
#include <hip/hip_bf16.h>
#include <hip/hip_fp16.h>

typedef unsigned int u32;
typedef unsigned short u16;
typedef __attribute__((ext_vector_type(8))) short short8;
typedef __attribute__((ext_vector_type(4))) float f32x4;

#define B_DIM 256
#define L_DIM 512
#define A_DIM 2048
#define W_DIM 64

__device__ __forceinline__ u32 fenc(float f){ u32 u=__float_as_uint(f); return (u>>31)? ~u : (u|0x80000000u); }
__device__ __forceinline__ float fdec(u32 k){ return (k>>31)? __uint_as_float(k&0x7FFFFFFFu) : __uint_as_float(~k); }
__device__ __forceinline__ u16 f2bf(float f){
  u32 u=__float_as_uint(f);
  u32 r=(u + 0x7FFFu + ((u>>16)&1u))>>16;
  return (u16)r;
}
__device__ __forceinline__ float bf2f(u16 b){ return __uint_as_float((u32)b << 16); }
__device__ __forceinline__ u16 f2h(float f){ _Float16 h = (_Float16)f; return __builtin_bit_cast(u16, h); }
__device__ __forceinline__ float h2f(u16 b){ _Float16 h = __builtin_bit_cast(_Float16, b); return (float)h; }

// f32 -> bf16 convert, n % 4 == 0
__global__ __launch_bounds__(256) void cvt_kernel(const float* __restrict__ src, u16* __restrict__ dst, int n){
  int stride = gridDim.x*blockDim.x*4;
  for (int i = (blockIdx.x*blockDim.x + threadIdx.x)*4; i < n; i += stride){
    float4 v = *(const float4*)(src + i);
    ushort4 o;
    o.x = f2bf(v.x); o.y = f2bf(v.y); o.z = f2bf(v.z); o.w = f2bf(v.w);
    *(ushort4*)(dst + i) = o;
  }
}

__device__ __forceinline__ void cvt_seg(const float* __restrict__ src, u16* __restrict__ dst, int n, int tid, int stride){
  for (int i = tid*4; i < n; i += stride){
    float4 v = *(const float4*)(src + i);
    ushort4 o;
    o.x = f2bf(v.x); o.y = f2bf(v.y); o.z = f2bf(v.z); o.w = f2bf(v.w);
    *(ushort4*)(dst + i) = o;
  }
}

__global__ __launch_bounds__(256) void cvt5_kernel(
    const float* s0, u16* d0, int n0,
    const float* s1, u16* d1, int n1,
    const float* s2, u16* d2, int n2,
    const float* s3, u16* d3, int n3,
    const float* s4, u16* d4, int n4){
  int tid = blockIdx.x*blockDim.x + threadIdx.x;
  int stride = gridDim.x*blockDim.x*4;
  cvt_seg(s0,d0,n0,tid,stride);
  cvt_seg(s1,d1,n1,tid,stride);
  cvt_seg(s2,d2,n2,tid,stride);
  cvt_seg(s3,d3,n3,tid,stride);
  cvt_seg(s4,d4,n4,tid,stride);
}

// ---------------------------------------------------------------------------
// 8-wave 256x256 pipelined NT GEMM (K=512 fixed, N=2048 fixed).
// C[m,n] = sum_k A[m,k]*B[n,k]. 4-slot LDS ring of 32-elem K-subtiles,
// counted vmcnt(4) (never 0 in steady state), raw s_barrier, setprio around
// MFMA, chunk-XOR LDS swizzle via pre-swizzled global source.
// MODE 0: store f16 + per-w (row/256) max.  MODE 1: store bf16.
// ---------------------------------------------------------------------------
template<int MODE>
__global__ __launch_bounds__(512, 2) void gemm8(
    const u16* __restrict__ Ab, const u16* __restrict__ Bb,
    u16* __restrict__ Cu, u32* __restrict__ menc)
{
  __shared__ u16 sl[4][2][256*32];   // 128 KiB: [slot][A=0/B=1][row*32+elem]
  __shared__ float wred[8];

  const int t = threadIdx.x;
  const int lane = t & 63;
  const int wv = t >> 6;             // 0..7
  const int wm = wv >> 2;            // 0..1  (m-half of 256)
  const int wn = wv & 3;             // 0..3  (64-col strip)

  // XCD-aware bijective swizzle (nwg = 8*64 = 512, % 8 == 0)
  const int id = blockIdx.x + gridDim.x*blockIdx.y;
  const int nwg = gridDim.x*gridDim.y;
  const int chunk = nwg >> 3;
  const int swz = (id & 7)*chunk + (id >> 3);
  const int bx = swz % gridDim.x;
  const int by = swz / gridDim.x;
  const int m0 = by*256, n0 = bx*256;
  const int Kd = L_DIM;

  f32x4 acc[8][4];
  #pragma unroll
  for (int i=0;i<8;++i)
    #pragma unroll
    for (int j=0;j<4;++j) acc[i][j] = (f32x4)0.f;

  const int cg = ((t&3) ^ ((t>>3)&3)) * 8;   // pre-swizzled source chunk (shorts)
  const int r0 = t >> 2;                      // staging row (and +128)
  const int fr = lane & 15;
  const int cx8 = ((lane>>4) ^ ((fr>>1)&3)) * 8;  // physical chunk on read

  auto STAGE = [&](int u){
    const u16* src = (u & 1) ? Bb : Ab;
    const int base = (u & 1) ? n0 : m0;
    const int su = u >> 1;
    u16* dst0 = &sl[su & 3][u & 1][t*8];
    const u16* g0 = src + (size_t)(base + r0)*Kd + su*32 + cg;
    __builtin_amdgcn_global_load_lds((const __attribute__((address_space(1))) u32*)g0,
        (__attribute__((address_space(3))) u32*)dst0, 16, 0, 0);
    __builtin_amdgcn_global_load_lds((const __attribute__((address_space(1))) u32*)(g0 + (size_t)128*Kd),
        (__attribute__((address_space(3))) u32*)(dst0 + 4096), 16, 0, 0);
  };

  // prologue: sub-tiles 0 and 1 (units 0..3)
  STAGE(0); STAGE(1); STAGE(2); STAGE(3);
  asm volatile("s_waitcnt vmcnt(4)" ::: "memory");  // units 0,1 (sub-tile 0) landed

  #pragma unroll
  for (int s = 0; s < 16; ++s){
    const u16* SA = &sl[s & 3][0][0];
    const u16* SB = &sl[s & 3][1][0];
    short8 a0[4], b0[4];

    // ---- phase even (m-half 0) ----
    if (s + 2 < 16) STAGE(2*(s+2));            // A of sub-tile s+2 -> slot (s+2)&3
    __builtin_amdgcn_s_barrier();
    asm volatile("" ::: "memory");
    #pragma unroll
    for (int jn=0;jn<4;++jn)
      b0[jn] = *(const short8*)(SB + (wn*64 + jn*16 + fr)*32 + cx8);
    #pragma unroll
    for (int i=0;i<4;++i)
      a0[i] = *(const short8*)(SA + (wm*128 + i*16 + fr)*32 + cx8);
    __builtin_amdgcn_s_setprio(1);
    #pragma unroll
    for (int i=0;i<4;++i)
      #pragma unroll
      for (int jn=0;jn<4;++jn)
        acc[i][jn] = __builtin_amdgcn_mfma_f32_16x16x32_bf16(a0[i], b0[jn], acc[i][jn], 0, 0, 0);
    __builtin_amdgcn_s_setprio(0);

    // ---- phase odd (m-half 1) ----
    if (s + 2 < 16){
      STAGE(2*(s+2)+1);                        // B of sub-tile s+2
      asm volatile("s_waitcnt vmcnt(4)" ::: "memory");  // sub-tile s+1 landed
    } else if (s == 14){
      asm volatile("s_waitcnt vmcnt(0)" ::: "memory");  // tail: drain for s=15
    }
    __builtin_amdgcn_s_barrier();
    asm volatile("" ::: "memory");
    #pragma unroll
    for (int i=0;i<4;++i)
      a0[i] = *(const short8*)(SA + (wm*128 + 64 + i*16 + fr)*32 + cx8);
    __builtin_amdgcn_s_setprio(1);
    #pragma unroll
    for (int i=0;i<4;++i)
      #pragma unroll
      for (int jn=0;jn<4;++jn)
        acc[4+i][jn] = __builtin_amdgcn_mfma_f32_16x16x32_bf16(a0[i], b0[jn], acc[4+i][jn], 0, 0, 0);
    __builtin_amdgcn_s_setprio(0);
  }

  // epilogue
  float vmax = -3.4e38f;
  #pragma unroll
  for (int h=0; h<2; ++h){
    #pragma unroll
    for (int i=0;i<4;++i){
      const int grow = m0 + wm*128 + h*64 + i*16 + ((lane>>4)<<2);
      #pragma unroll
      for (int jn=0;jn<4;++jn){
        const int gcol = n0 + wn*64 + jn*16 + fr;
        #pragma unroll
        for (int r=0;r<4;++r){
          float v = acc[h*4+i][jn][r];
          const size_t idx = (size_t)(grow + r)*A_DIM + gcol;
          if constexpr (MODE == 0){ Cu[idx] = f2h(v); vmax = fmaxf(vmax, v); }
          else Cu[idx] = f2bf(v);
        }
      }
    }
  }
  if constexpr (MODE == 0){
    #pragma unroll
    for (int off=32; off; off>>=1) vmax = fmaxf(vmax, __shfl_xor(vmax, off));
    if (lane == 0) wred[wv] = vmax;
    __syncthreads();
    if (t == 0){
      float m = wred[0];
      #pragma unroll
      for (int i=1;i<8;++i) m = fmaxf(m, wred[i]);
      atomicMax(menc + (m0 >> 8), fenc(m));
    }
  }
}

// small NT GEMM (128x128, 4 waves): MODE 2: store f32 (Q), MODE 3: store f32 (out)
template<int MODE>
__global__ __launch_bounds__(256) void gemm_nt(
    const u16* __restrict__ Ab, const u16* __restrict__ Bb,
    float* __restrict__ Cf, int N, int Kd)
{
  __shared__ u16 As[128*32];
  __shared__ u16 Bs[128*32];

  const int t = threadIdx.x;
  const int lane = t & 63;
  const int wave = t >> 6;
  const int wm = wave >> 1, wn = wave & 1;

  const int nwg = gridDim.x * gridDim.y;
  const int id = blockIdx.x + gridDim.x * blockIdx.y;
  const int chunk = nwg >> 3;
  const int swz = (id & 7) * chunk + (id >> 3);
  const int bx = swz % gridDim.x;
  const int by = swz / gridDim.x;
  const int m0 = by * 128;
  const int n0 = bx * 128;

  f32x4 acc[4][4];
  #pragma unroll
  for (int i=0;i<4;++i)
    #pragma unroll
    for (int j=0;j<4;++j) acc[i][j] = (f32x4)0.f;

  const int row_in = t >> 2;
  const int cg = ((t&3) ^ ((t>>3)&3)) * 8;
  const int wbase = (t & 192) * 8;

  const int nK = Kd >> 5;
  for (int kt = 0; kt < nK; ++kt){
    const int k0 = kt << 5;
    #pragma unroll
    for (int i = 0; i < 2; ++i){
      const u16* ga = Ab + (size_t)(m0 + i*64 + row_in)*Kd + k0 + cg;
      const u16* gb = Bb + (size_t)(n0 + i*64 + row_in)*Kd + k0 + cg;
      __builtin_amdgcn_global_load_lds((const __attribute__((address_space(1))) u32*)ga,
          (__attribute__((address_space(3))) u32*)(As + i*2048 + wbase), 16, 0, 0);
      __builtin_amdgcn_global_load_lds((const __attribute__((address_space(1))) u32*)gb,
          (__attribute__((address_space(3))) u32*)(Bs + i*2048 + wbase), 16, 0, 0);
    }
    __syncthreads();
    short8 af[4], bf[4];
    const int fr = lane & 15;
    const int k = lane >> 4;
    #pragma unroll
    for (int i=0;i<4;++i){
      const int rowA = wm*64 + i*16 + fr;
      const int rowB = wn*64 + i*16 + fr;
      af[i] = *(const short8*)(As + rowA*32 + (k ^ ((rowA>>1)&3))*8);
      bf[i] = *(const short8*)(Bs + rowB*32 + (k ^ ((rowB>>1)&3))*8);
    }
    #pragma unroll
    for (int i=0;i<4;++i)
      #pragma unroll
      for (int j=0;j<4;++j)
        acc[i][j] = __builtin_amdgcn_mfma_f32_16x16x32_bf16(af[i], bf[j], acc[i][j], 0, 0, 0);
    __syncthreads();
  }

  #pragma unroll
  for (int i=0;i<4;++i){
    const int grow_base = m0 + wm*64 + i*16 + ((lane>>4)<<2);
    #pragma unroll
    for (int j=0;j<4;++j){
      const int gcol = n0 + wn*64 + j*16 + (lane & 15);
      #pragma unroll
      for (int r=0;r<4;++r)
        Cf[(size_t)(grow_base + r)*N + gcol] = acc[i][j][r];
    }
  }
}

// context + gating, 4 elems/thread
__global__ __launch_bounds__(256) void reduce_kernel(
    const u16* __restrict__ Kh, const u16* __restrict__ Vb,
    const float* __restrict__ Qf, const u32* __restrict__ menc,
    u16* __restrict__ g)
{
  __shared__ float ms[W_DIM];
  if (threadIdx.x < W_DIM) ms[threadIdx.x] = fdec(menc[threadIdx.x]);
  __syncthreads();
  const int total = B_DIM * A_DIM;
  const int idx = (blockIdx.x*blockDim.x + threadIdx.x) * 4;

  float num0=0.f, num1=0.f, num2=0.f, num3=0.f;
  float den0=1e-8f, den1=1e-8f, den2=1e-8f, den3=1e-8f;
  #pragma unroll 2
  for (int w = 0; w < W_DIM; ++w){
    const size_t off = (size_t)w*total + idx;
    ushort4 kh = *(const ushort4*)(Kh + off);
    ushort4 vb = *(const ushort4*)(Vb + off);
    const float mw = ms[w];
    float e0 = __expf(h2f(kh.x) - mw); num0 += e0*bf2f(vb.x); den0 += e0;
    float e1 = __expf(h2f(kh.y) - mw); num1 += e1*bf2f(vb.y); den1 += e1;
    float e2 = __expf(h2f(kh.z) - mw); num2 += e2*bf2f(vb.z); den2 += e2;
    float e3 = __expf(h2f(kh.w) - mw); num3 += e3*bf2f(vb.w); den3 += e3;
  }
  float4 q = *(const float4*)(Qf + idx);
  ushort4 o;
  o.x = f2bf(num0/den0/(1.f + __expf(-q.x)));
  o.y = f2bf(num1/den1/(1.f + __expf(-q.y)));
  o.z = f2bf(num2/den2/(1.f + __expf(-q.z)));
  o.w = f2bf(num3/den3/(1.f + __expf(-q.w)));
  *(ushort4*)(g + idx) = o;
}

extern "C" void kernel_launch(void* const* d_in, const int* in_sizes, int n_in,
                              void* d_out, int out_size, void* d_ws, size_t ws_size,
                              hipStream_t stream){
  const float* zc = (const float*)d_in[0];
  const float* zw = (const float*)d_in[1];
  const float* Wq = (const float*)d_in[2];
  const float* Wk = (const float*)d_in[3];
  const float* Wv = (const float*)d_in[4];
  const float* Wo = (const float*)d_in[5];
  float* out = (float*)d_out;

  char* ws = (char*)d_ws;
  size_t off = 0;
  auto alloc = [&](size_t bytes)->void*{ void* p = ws + off; off += (bytes + 255) & ~(size_t)255; return p; };
  u16*  Zb   = (u16*) alloc((size_t)W_DIM*B_DIM*L_DIM*2);
  u16*  zcb  = (u16*) alloc((size_t)B_DIM*L_DIM*2);
  u16*  Wqb  = (u16*) alloc((size_t)A_DIM*L_DIM*2);
  u16*  Wkb  = (u16*) alloc((size_t)A_DIM*L_DIM*2);
  u16*  Wvb  = (u16*) alloc((size_t)A_DIM*L_DIM*2);
  u16*  Wob  = (u16*) alloc((size_t)L_DIM*A_DIM*2);
  u16*  Kh   = (u16*) alloc((size_t)W_DIM*B_DIM*A_DIM*2);   // f16
  u16*  Vb   = (u16*) alloc((size_t)W_DIM*B_DIM*A_DIM*2);   // bf16
  float* Qf  = (float*)alloc((size_t)B_DIM*A_DIM*4);
  u16*  g    = (u16*) alloc((size_t)B_DIM*A_DIM*2);
  u32*  menc = (u32*) alloc(W_DIM*4);

  cvt_kernel<<<512, 256, 0, stream>>>(zw, Zb, W_DIM*B_DIM*L_DIM);
  cvt5_kernel<<<256, 256, 0, stream>>>(zc, zcb, B_DIM*L_DIM,
                                       Wq, Wqb, A_DIM*L_DIM,
                                       Wk, Wkb, A_DIM*L_DIM,
                                       Wv, Wvb, A_DIM*L_DIM,
                                       Wo, Wob, L_DIM*A_DIM);
  hipMemsetAsync(menc, 0, W_DIM*4, stream);

  // K (f16 + per-w max) and V (bf16): M=16384, N=2048, grid 8x64 = 512 wgs
  gemm8<0><<<dim3(A_DIM/256, (W_DIM*B_DIM)/256), 512, 0, stream>>>(Zb, Wkb, Kh, menc);
  gemm8<1><<<dim3(A_DIM/256, (W_DIM*B_DIM)/256), 512, 0, stream>>>(Zb, Wvb, Vb, nullptr);
  // Q = zc @ Wq^T -> f32 (grid 16x2)
  gemm_nt<2><<<dim3(A_DIM/128, B_DIM/128), 256, 0, stream>>>(zcb, Wqb, Qf, A_DIM, L_DIM);
  // g = sigmoid(Q) * context
  reduce_kernel<<<(B_DIM*A_DIM)/(256*4), 256, 0, stream>>>(Kh, Vb, Qf, menc, g);
  // out = g @ Wo^T (grid 4x2)
  gemm_nt<3><<<dim3(L_DIM/128, B_DIM/128), 256, 0, stream>>>(g, Wob, out, L_DIM, A_DIM);
}